// Round 2
// baseline (169.524 us; speedup 1.0000x reference)
//
#include <hip/hip_runtime.h>
#include <hip/hip_bf16.h>
#include <cstdint>
#include <cstddef>

typedef short short8 __attribute__((ext_vector_type(8)));
typedef float f32x4 __attribute__((ext_vector_type(4)));
typedef float f32x2 __attribute__((ext_vector_type(2)));

#define NS    2048
#define KPAD  288
#define H2    512
#define HID   256
#define WPB   7       // windows per sig workgroup (192 thr = 3 waves = 3 thirds)
#define SBLK  293     // ceil(2048/7)

#define MFMA(a,b,c) __builtin_amdgcn_mfma_f32_16x16x32_bf16((a),(b),(c),0,0,0)

__device__ __forceinline__ void gl2lds16(const void* g, void* l) {
    __builtin_amdgcn_global_load_lds(
        (const __attribute__((address_space(1))) void*)g,
        (__attribute__((address_space(3))) void*)l, 16, 0, 0);
}
__device__ __forceinline__ float geluf(float x) {
    return 0.5f * x * (1.0f + erff(x * 0.70710678118654752f));
}
__device__ __forceinline__ f32x4 shfl4(f32x4 v, int d) {
    f32x4 r;
    r[0] = __shfl_xor(v[0], d); r[1] = __shfl_xor(v[1], d);
    r[2] = __shfl_xor(v[2], d); r[3] = __shfl_xor(v[3], d);
    return r;
}

struct Tbl3 { short col[729]; };
static constexpr Tbl3 make_tbl3() {
    Tbl3 t{};
    for (int x = 0; x < 729; ++x) t.col[x] = -1;
    int r = 0;
    for (int i = 0; i < 9; ++i)
        for (int j = 0; j < 9; ++j)
            for (int k = 0; k < 9; ++k) {
                bool lt1 = (i < j) || (i == j && (j < k || (j == k && k < i)));
                bool lt2 = (i < k) || (i == k && (j < i || (j == i && k < j)));
                if (lt1 && lt2) { t.col[(i*9+j)*9+k] = (short)(45 + r); ++r; }
            }
    return t;
}
static constexpr Tbl3 TBL3 = make_tbl3();

// ============================================================================
// sig: unchanged (control). LDS+latency bound, ~48us measured.
// ============================================================================
#define SIG_STEP(VA_,VB_,VC_) { \
    const float hh = 0.5f * S1i + vi * (1.0f/6.0f); \
    const float ra = S2ra + hh * (VA_); \
    const float rb = S2rb + hh * (VB_); \
    const float rc = S2rc + hh * (VC_); \
    const f32x2 ra2 = {ra, ra}, rb2 = {rb, rb}, rc2 = {rc, rc}; \
    S3sa += ra * v0; S3pa0 += ra2*vp0; S3pa1 += ra2*vp1; S3pa2 += ra2*vp2; S3pa3 += ra2*vp3; \
    S3sb += rb * v0; S3pb0 += rb2*vp0; S3pb1 += rb2*vp1; S3pb2 += rb2*vp2; S3pb3 += rb2*vp3; \
    S3sc += rc * v0; S3pc0 += rc2*vp0; S3pc1 += rc2*vp1; S3pc2 += rc2*vp2; S3pc3 += rc2*vp3; \
    const float aa = S1i + 0.5f * vi; \
    S2ra += aa * (VA_); S2rb += aa * (VB_); S2rc += aa * (VC_); \
    S1i += vi; }

#define SIG_MAIN(VA_,VB_,VC_) { \
    { const float* xr = &X[(g0 - lo) * 8]; \
      const float4 e0 = *(const float4*)xr; \
      const float4 e1 = *(const float4*)(xr + 4); \
      const float rs = xr[ioff]; \
      const float v0 = 0.0f; \
      const f32x2 vp0 = {e0.x, e0.y}, vp1 = {e0.z, e0.w}, vp2 = {e1.x, e1.y}, vp3 = {e1.z, e1.w}; \
      const float vi = (ci == 0) ? 0.0f : rs; \
      SIG_STEP(VA_,VB_,VC_) } \
    const float* pd = &PD[(sm59 + 1 - lo + 59) * 8]; \
    float4 d0 = *(const float4*)pd; \
    float4 d1 = *(const float4*)(pd + 4); \
    float rn = pd[ioff]; \
    _Pragma("unroll 2") \
    for (int j = 1; j < 60; ++j) { \
      const float4 e0 = d0; const float4 e1 = d1; const float rs = rn; \
      pd += 8; \
      d0 = *(const float4*)pd; d1 = *(const float4*)(pd + 4); rn = pd[ioff]; \
      const float v0 = DT; \
      const f32x2 vp0 = {e0.x, e0.y}, vp1 = {e0.z, e0.w}, vp2 = {e1.x, e1.y}, vp3 = {e1.z, e1.w}; \
      const float vi = (ci == 0) ? DT : rs; \
      SIG_STEP(VA_,VB_,VC_) \
    } }

#define SIG_ST(RA,RB,RC) \
    if (act) { \
        if ((RA) == 0) S1buf[widx * 9 + ci] = S1i; \
        float* sb = &S2buf[widx * 81 + ci * 9]; \
        sb[RA] = S2ra; sb[RB] = S2rb; sb[RC] = S2rc; \
    }

#define S3EL0(SL) S3s##SL
#define S3EL1(SL) S3p##SL##0[0]
#define S3EL2(SL) S3p##SL##0[1]
#define S3EL3(SL) S3p##SL##1[0]
#define S3EL4(SL) S3p##SL##1[1]
#define S3EL5(SL) S3p##SL##2[0]
#define S3EL6(SL) S3p##SL##2[1]
#define S3EL7(SL) S3p##SL##3[0]
#define S3EL8(SL) S3p##SL##3[1]

#define SIG_E2(SL,J2) if (ci < (J2)) { \
    const float val2 = S2r##SL - 0.5f * S1i * s1v##J2; \
    const int col2 = 9 + ci*8 - (ci*(ci-1))/2 + ((J2) - ci - 1); \
    frow[col2] = __float2bfloat16(val2); }

#define SIG_E3(SL,R,K) { const int col3 = TBL3.col[tb + (R)*9 + (K)]; \
    if (col3 >= 0) { \
        const float val3 = S3EL##K(SL) \
            - 0.5f * (S1i * S2w[(R)*9+(K)] + S2r##SL * s1v##K) \
            + S1i * s1v##R * s1v##K * (1.0f/3.0f); \
        frow[col3] = __float2bfloat16(val3); } }

#define SIG_E3R(SL,R) SIG_E3(SL,R,0) SIG_E3(SL,R,1) SIG_E3(SL,R,2) SIG_E3(SL,R,3) \
    SIG_E3(SL,R,4) SIG_E3(SL,R,5) SIG_E3(SL,R,6) SIG_E3(SL,R,7) SIG_E3(SL,R,8)

#define SIG_EMIT(RA,RB,RC) \
    if (act) { \
        if ((RA) == 0) { \
            frow[ci] = __float2bfloat16(S1i); \
            if (ci == 0) { \
                const __hip_bfloat16 z16 = __float2bfloat16(0.0f); \
                frow[285] = z16; frow[286] = z16; frow[287] = z16; \
            } \
        } \
        SIG_E2(a,RA) SIG_E2(b,RB) SIG_E2(c,RC) \
        SIG_E3R(a,RA) SIG_E3R(b,RB) SIG_E3R(c,RC) \
    }

__global__ __launch_bounds__(192) __attribute__((amdgpu_waves_per_eu(1, 6)))
void sig_kernel(const float* __restrict__ x, __hip_bfloat16* __restrict__ feats) {
    __shared__ __align__(16) float X[66 * 8];
    __shared__ __align__(16) float PD[126 * 8];   // rows 0..58 zero pad, 59+r = x[lo+r]-x[lo+r-1]
    __shared__ float S2buf[WPB * 81];
    __shared__ float S1buf[WPB * 9];

    const int blk = blockIdx.x;
    const int b   = blk / SBLK;
    const int s0  = (blk % SBLK) * WPB;
    const int lo  = (s0 - 59 > 0) ? (s0 - 59) : 0;
    const int hi  = (s0 + WPB - 1 < NS - 1) ? (s0 + WPB - 1) : (NS - 1);
    const int nrow = hi - lo + 1;     // <= 66
    const int tid = threadIdx.x;

    {   // stage x rows
        const float4* src = (const float4*)(x + ((size_t)b * NS + lo) * 8);
        float4* X4 = (float4*)X;
        const int n4 = nrow * 2;
        for (int t = tid; t < n4; t += 192) X4[t] = src[t];
    }
    __syncthreads();
    {   // build padded diff rows
        const float4* X4 = (const float4*)X;
        float4* PD4 = (float4*)PD;
        for (int t = tid; t < 252; t += 192) {
            const int p = t >> 1;         // padded row
            const int r = p - 59;         // diff row
            float4 dv = {0.f, 0.f, 0.f, 0.f};
            if (r > 0 && r < nrow) {
                const float4 a = X4[t - 118], bb = X4[t - 120];
                dv.x = a.x - bb.x; dv.y = a.y - bb.y; dv.z = a.z - bb.z; dv.w = a.w - bb.w;
            }
            PD4[t] = dv;
        }
    }
    __syncthreads();

    const int t3    = tid >> 6;           // third (wave-uniform): rows {0,1,2}/{3,4,5}/{6,7,8}
    const int lt    = tid & 63;
    const int widx0 = lt / 9;             // 0..7 (lane 63 idle)
    const int ci    = lt - widx0 * 9;     // slab index 0..8
    const bool act  = (lt < 63) && (s0 + widx0 < NS);
    const int widx  = (widx0 < WPB - 1) ? widx0 : WPB - 1;
    int s = s0 + widx; if (s > NS - 1) s = NS - 1;

    float S3sa=0.f, S3sb=0.f, S3sc=0.f;
    f32x2 S3pa0={0.f,0.f},S3pa1={0.f,0.f},S3pa2={0.f,0.f},S3pa3={0.f,0.f};
    f32x2 S3pb0={0.f,0.f},S3pb1={0.f,0.f},S3pb2={0.f,0.f},S3pb3={0.f,0.f};
    f32x2 S3pc0={0.f,0.f},S3pc1={0.f,0.f},S3pc2={0.f,0.f},S3pc3={0.f,0.f};
    float S2ra=0.f, S2rb=0.f, S2rc=0.f;
    float S1i = 0.f;
    const int ioff = (ci > 0) ? (ci - 1) : 0;
    const int sm59 = s - 59;
    const int g0   = (sm59 > 0) ? sm59 : 0;
    const float DT = 1.0f / 59.0f;

    if (t3 == 0)      { SIG_MAIN(v0,   e0.x, e0.y) }
    else if (t3 == 1) { SIG_MAIN(e0.z, e0.w, e1.x) }
    else              { SIG_MAIN(e1.y, e1.z, e1.w) }

    if (t3 == 0)      { SIG_ST(0,1,2) }
    else if (t3 == 1) { SIG_ST(3,4,5) }
    else              { SIG_ST(6,7,8) }
    __syncthreads();

    const float* s1p = &S1buf[widx * 9];
    const float s1v0=s1p[0], s1v1=s1p[1], s1v2=s1p[2], s1v3=s1p[3], s1v4=s1p[4];
    const float s1v5=s1p[5], s1v6=s1p[6], s1v7=s1p[7], s1v8=s1p[8];
    const float* S2w = &S2buf[widx * 81];
    const int tb = ci * 81;
    __hip_bfloat16* frow = feats + (size_t)(b * NS + s) * KPAD;

    if (t3 == 0)      { SIG_EMIT(0,1,2) }
    else if (t3 == 1) { SIG_EMIT(3,4,5) }
    else              { SIG_EMIT(6,7,8) }
}

// ============================================================================
// prep: fused convert_w1 + convert_w2g + stats-zero.
// w1T now stride 320 (40 x 16B blocks per row, zero-padded) for swizzled
// full-K staging in gemm1.
// ============================================================================
__global__ __launch_bounds__(512)
void prep_kernel(const float* __restrict__ w1, const float* __restrict__ w2,
                 const float* __restrict__ lng, const float* __restrict__ lnb,
                 const float* __restrict__ b2,
                 __hip_bfloat16* __restrict__ w1T, __hip_bfloat16* __restrict__ w2g,
                 float* __restrict__ gw, float* __restrict__ cvec,
                 float* __restrict__ stats) {
    const int blk = blockIdx.x;
    if (blk < 256) {
        const int n = blk, k = threadIdx.x;
        const float wv = w2[(size_t)k * HID + n];
        const float a = lng[k] * wv;
        const float c = lnb[k] * wv;
        w2g[(size_t)n * H2 + k] = __float2bfloat16(a);
        float ra = a, rc = c;
#pragma unroll
        for (int d = 1; d < 64; d <<= 1) { ra += __shfl_xor(ra, d); rc += __shfl_xor(rc, d); }
        __shared__ float r1[8], r2[8];
        const int wv_ = k >> 6, ln = k & 63;
        if (ln == 0) { r1[wv_] = ra; r2[wv_] = rc; }
        __syncthreads();
        if (k == 0) {
            float sa = 0.f, sc = 0.f;
#pragma unroll
            for (int i = 0; i < 8; ++i) { sa += r1[i]; sc += r2[i]; }
            gw[n] = sa; cvec[n] = sc + b2[n];
        }
    } else {
        const int n = blk - 256;           // 0..511
        const int k = threadIdx.x;
        if (k < 320) {
            const float v = (k < 285) ? w1[(size_t)k * H2 + n] : 0.0f;
            w1T[(size_t)n * 320 + k] = __float2bfloat16(v);
        }
        if (k < 64) stats[n * 64 + k] = 0.0f;   // 512*64 = 32768 floats
    }
}

// ============================================================================
// GEMM1: 64x64 tiles, grid (8-nfast, 256-m) = 2048 blocks, 2 resident/CU.
// Full-K (288) staged once into XOR-swizzled LDS -> ONE barrier -> 9 ksteps
// with zero inner barriers. Swizzle: 16B-block index ^= (row&7), applied to
// the GLOBAL source during global_load_lds (linear LDS dest) and to the
// ds_read address (rule 21: both-sides involution).
// ============================================================================
__global__ __launch_bounds__(256)
void gemm1_kernel(const __hip_bfloat16* __restrict__ feats,
                  const __hip_bfloat16* __restrict__ w1T,
                  const float* __restrict__ bias,
                  __hip_bfloat16* __restrict__ h1,
                  float* __restrict__ stats) {
    __shared__ __align__(16) __hip_bfloat16 ldsA[64 * 320];   // 40 KB (stride 640B = 40 blks)
    __shared__ __align__(16) __hip_bfloat16 ldsB[64 * 320];   // 40 KB
    const int tid  = threadIdx.x;
    const int wave = tid >> 6;
    const int lane = tid & 63;
    const int quad = lane >> 4;
    const int l16  = lane & 15;
    const int mh   = (wave >> 1) * 32;
    const int nh   = (wave & 1) * 32;
    const int n0   = blockIdx.x * 64;     // n fast-varying: consecutive blocks share A slice
    const int m0   = blockIdx.y * 64;

    const char* Ab = (const char*)feats;  // row stride 576 B (read up to 640B: spills into h1 ws, harmless)
    const char* Bb = (const char*)w1T;    // row stride 640 B exactly
#pragma unroll
    for (int t = 0; t < 10; ++t) {
        const int L   = tid + t * 256;        // dest 16B-block index, 0..2559
        const int row = L / 40;
        const int blk = L - row * 40;
        const int sb  = (blk ^ (row & 7)) * 16;
        gl2lds16(Ab + (size_t)(m0 + row) * 576 + sb, (char*)ldsA + (L & ~63) * 16);
        gl2lds16(Bb + (size_t)(n0 + row) * 640 + sb, (char*)ldsB + (L & ~63) * 16);
    }
    __syncthreads();

    f32x4 acc00={0,0,0,0}, acc01={0,0,0,0}, acc10={0,0,0,0}, acc11={0,0,0,0};
    const int x0 = (l16 & 7) << 4;            // (row&7)<<4, same for row and row+16
    const char* A0 = (const char*)ldsA + (mh + l16) * 640;
    const char* A1 = A0 + 16 * 640;
    const char* B0 = (const char*)ldsB + (nh + l16) * 640;
    const char* B1 = B0 + 16 * 640;
#pragma unroll
    for (int kt = 0; kt < 9; ++kt) {
        const int ka = (kt * 64 + quad * 16) ^ x0;
        const short8 a0 = *(const short8*)(A0 + ka);
        const short8 a1 = *(const short8*)(A1 + ka);
        const short8 b0 = *(const short8*)(B0 + ka);
        const short8 b1 = *(const short8*)(B1 + ka);
        acc00 = MFMA(a0, b0, acc00); acc01 = MFMA(a0, b1, acc01);
        acc10 = MFMA(a1, b0, acc10); acc11 = MFMA(a1, b1, acc11);
    }

    f32x4 sum0={0,0,0,0}, sum1={0,0,0,0}, sq0={0,0,0,0}, sq1={0,0,0,0};
#define G1EP(mf,nf,ACC) { \
    const int colv = n0 + nh + (nf)*16 + l16; \
    const float bv = bias[colv]; \
    f32x4 e; \
    e[0] = geluf(ACC[0] + bv); e[1] = geluf(ACC[1] + bv); \
    e[2] = geluf(ACC[2] + bv); e[3] = geluf(ACC[3] + bv); \
    const int rrow = m0 + mh + (mf)*16 + quad*4; \
    h1[(size_t)(rrow+0)*H2 + colv] = __float2bfloat16(e[0]); \
    h1[(size_t)(rrow+1)*H2 + colv] = __float2bfloat16(e[1]); \
    h1[(size_t)(rrow+2)*H2 + colv] = __float2bfloat16(e[2]); \
    h1[(size_t)(rrow+3)*H2 + colv] = __float2bfloat16(e[3]); \
    sum##mf += e; sq##mf += e*e; }
    G1EP(0,0,acc00) G1EP(0,1,acc01) G1EP(1,0,acc10) G1EP(1,1,acc11)
#define G1RED(mf) { \
    f32x4 s = sum##mf, q = sq##mf; \
    s += shfl4(s,1); q += shfl4(q,1); s += shfl4(s,2); q += shfl4(q,2); \
    s += shfl4(s,4); q += shfl4(q,4); s += shfl4(s,8); q += shfl4(q,8); \
    if (l16 == 0) { const int rrow = m0 + mh + (mf)*16 + quad*4; \
        atomicAdd(&stats[2*(rrow+0)],   s[0]); atomicAdd(&stats[2*(rrow+0)+1], q[0]); \
        atomicAdd(&stats[2*(rrow+1)],   s[1]); atomicAdd(&stats[2*(rrow+1)+1], q[1]); \
        atomicAdd(&stats[2*(rrow+2)],   s[2]); atomicAdd(&stats[2*(rrow+2)+1], q[2]); \
        atomicAdd(&stats[2*(rrow+3)],   s[3]); atomicAdd(&stats[2*(rrow+3)+1], q[3]); } }
    G1RED(0) G1RED(1)
}

// ============================================================================
// GEMM2: 64x64 tiles, grid (4-nfast, 256-m) = 1024 blocks, 2 resident/CU.
// K=512 in 4 chunks of BK=128, double-buffered; next-chunk loads issued
// BEFORE the compute so their latency hides under the MFMAs; one barrier
// per chunk. Same both-sides XOR swizzle.
// ============================================================================
__global__ __launch_bounds__(256)
void gemm2_kernel(const __hip_bfloat16* __restrict__ h1,
                  const __hip_bfloat16* __restrict__ w2g,
                  const float* __restrict__ stats,
                  const float* __restrict__ gw,
                  const float* __restrict__ cvec,
                  float* __restrict__ out) {
    __shared__ __align__(16) __hip_bfloat16 ldsA[2][64 * 128];  // 16 KB each
    __shared__ __align__(16) __hip_bfloat16 ldsB[2][64 * 128];
    const int tid  = threadIdx.x;
    const int wave = tid >> 6;
    const int lane = tid & 63;
    const int quad = lane >> 4;
    const int l16  = lane & 15;
    const int mh   = (wave >> 1) * 32;
    const int nh   = (wave & 1) * 32;
    const int n0   = blockIdx.x * 64;     // n fast-varying
    const int m0   = blockIdx.y * 64;

    const char* Ab = (const char*)h1;     // row stride 1024 B
    const char* Bb = (const char*)w2g;    // row stride 1024 B

#define G2STAGE(S, BUF) { \
    _Pragma("unroll") \
    for (int t = 0; t < 4; ++t) { \
        const int L   = tid + t * 256;     /* 0..1023 */ \
        const int row = L >> 4; \
        const int blk = L & 15; \
        const int sb  = (S) * 256 + ((blk ^ (row & 7)) * 16); \
        gl2lds16(Ab + (size_t)(m0 + row) * 1024 + sb, (char*)ldsA[BUF] + (L & ~63) * 16); \
        gl2lds16(Bb + (size_t)(n0 + row) * 1024 + sb, (char*)ldsB[BUF] + (L & ~63) * 16); \
    } }

    f32x4 acc00={0,0,0,0}, acc01={0,0,0,0}, acc10={0,0,0,0}, acc11={0,0,0,0};
    const int x0 = (l16 & 7) << 4;

#define G2COMP(BUF) { \
    const char* A0 = (const char*)ldsA[BUF] + (mh + l16) * 256; \
    const char* A1 = A0 + 16 * 256; \
    const char* B0 = (const char*)ldsB[BUF] + (nh + l16) * 256; \
    const char* B1 = B0 + 16 * 256; \
    _Pragma("unroll") \
    for (int kt = 0; kt < 4; ++kt) { \
        const int ka = (kt * 64 + quad * 16) ^ x0; \
        const short8 a0 = *(const short8*)(A0 + ka); \
        const short8 a1 = *(const short8*)(A1 + ka); \
        const short8 b0 = *(const short8*)(B0 + ka); \
        const short8 b1 = *(const short8*)(B1 + ka); \
        acc00 = MFMA(a0, b0, acc00); acc01 = MFMA(a0, b1, acc01); \
        acc10 = MFMA(a1, b0, acc10); acc11 = MFMA(a1, b1, acc11); \
    } }

    G2STAGE(0, 0)
    __syncthreads();
#pragma unroll 1
    for (int s = 0; s < 4; ++s) {
        if (s < 3) { G2STAGE(s + 1, (s + 1) & 1) }
        G2COMP(s & 1)
        __syncthreads();
    }

#define G2EP(mf, ACC0, ACC1) { \
    const int rrow = m0 + mh + (mf)*16 + quad*4; \
    f32x4 muv, rsv; \
    _Pragma("unroll") \
    for (int r = 0; r < 4; ++r) { \
        const float su = stats[2*(rrow+r)]; const float qu = stats[2*(rrow+r)+1]; \
        const float m_ = su * (1.0f/512.0f); const float v_ = qu * (1.0f/512.0f) - m_*m_; \
        muv[r] = m_; rsv[r] = rsqrtf(v_ + 1e-5f); } \
    { const int colv = n0 + nh + l16; \
      const float g_ = gw[colv], c_ = cvec[colv]; \
      out[(size_t)(rrow+0)*HID + colv] = rsv[0]*(ACC0[0] - muv[0]*g_) + c_; \
      out[(size_t)(rrow+1)*HID + colv] = rsv[1]*(ACC0[1] - muv[1]*g_) + c_; \
      out[(size_t)(rrow+2)*HID + colv] = rsv[2]*(ACC0[2] - muv[2]*g_) + c_; \
      out[(size_t)(rrow+3)*HID + colv] = rsv[3]*(ACC0[3] - muv[3]*g_) + c_; } \
    { const int colv = n0 + nh + 16 + l16; \
      const float g_ = gw[colv], c_ = cvec[colv]; \
      out[(size_t)(rrow+0)*HID + colv] = rsv[0]*(ACC1[0] - muv[0]*g_) + c_; \
      out[(size_t)(rrow+1)*HID + colv] = rsv[1]*(ACC1[1] - muv[1]*g_) + c_; \
      out[(size_t)(rrow+2)*HID + colv] = rsv[2]*(ACC1[2] - muv[2]*g_) + c_; \
      out[(size_t)(rrow+3)*HID + colv] = rsv[3]*(ACC1[3] - muv[3]*g_) + c_; } }
    G2EP(0, acc00, acc01)
    G2EP(1, acc10, acc11)
}

// ============================================================================
extern "C" void kernel_launch(void* const* d_in, const int* in_sizes, int n_in,
                              void* d_out, int out_size, void* d_ws, size_t ws_size,
                              hipStream_t stream) {
    const float* x   = (const float*)d_in[0];
    const float* w1  = (const float*)d_in[1];
    const float* b1  = (const float*)d_in[2];
    const float* lng = (const float*)d_in[3];
    const float* lnb = (const float*)d_in[4];
    const float* w2  = (const float*)d_in[5];
    const float* b2  = (const float*)d_in[6];
    float* out = (float*)d_out;

    char* ws = (char*)d_ws;
    __hip_bfloat16* feats = (__hip_bfloat16*)(ws);                        // 9437184
    __hip_bfloat16* h1    = (__hip_bfloat16*)(ws + 9437184);              // 16777216
    __hip_bfloat16* w1T   = (__hip_bfloat16*)(ws + 26214400);             // 327680 (512 x 320)
    __hip_bfloat16* w2g   = (__hip_bfloat16*)(ws + 26542080);             // 262144
    float*          gw    = (float*)(ws + 26804224);                      // 4096
    float*          cvec  = (float*)(ws + 26808320);                      // 4096
    float*          stats = (float*)(ws + 26812416);                      // 131072

    prep_kernel<<<dim3(768), dim3(512), 0, stream>>>(w1, w2, lng, lnb, b2,
                                                     w1T, w2g, gw, cvec, stats);
    sig_kernel<<<dim3(8 * SBLK), dim3(192), 0, stream>>>(x, feats);
    gemm1_kernel<<<dim3(8, 256), dim3(256), 0, stream>>>(feats, w1T, b1, h1, stats);
    gemm2_kernel<<<dim3(4, 256), dim3(256), 0, stream>>>(h1, w2g, stats, gw, cvec, out);
}

// Round 3
// 168.661 us; speedup vs baseline: 1.0051x; 1.0051x over previous
//
#include <hip/hip_runtime.h>
#include <hip/hip_bf16.h>
#include <cstdint>
#include <cstddef>

typedef short short8 __attribute__((ext_vector_type(8)));
typedef float f32x4 __attribute__((ext_vector_type(4)));
typedef float f32x2 __attribute__((ext_vector_type(2)));

#define NS    2048
#define KPAD  288
#define H2    512
#define HID   256
#define WPB   7       // windows per sig workgroup
#define SBLK  293     // ceil(2048/7)

#define MFMA(a,b,c) __builtin_amdgcn_mfma_f32_16x16x32_bf16((a),(b),(c),0,0,0)

__device__ __forceinline__ void gl2lds16(const void* g, void* l) {
    __builtin_amdgcn_global_load_lds(
        (const __attribute__((address_space(1))) void*)g,
        (__attribute__((address_space(3))) void*)l, 16, 0, 0);
}
__device__ __forceinline__ float geluf(float x) {
    return 0.5f * x * (1.0f + erff(x * 0.70710678118654752f));
}
__device__ __forceinline__ f32x4 shfl4(f32x4 v, int d) {
    f32x4 r;
    r[0] = __shfl_xor(v[0], d); r[1] = __shfl_xor(v[1], d);
    r[2] = __shfl_xor(v[2], d); r[3] = __shfl_xor(v[3], d);
    return r;
}
__device__ __forceinline__ f32x2 mk2(float a, float b) { f32x2 r; r[0] = a; r[1] = b; return r; }

struct Tbl3 { short col[729]; };
static constexpr Tbl3 make_tbl3() {
    Tbl3 t{};
    for (int x = 0; x < 729; ++x) t.col[x] = -1;
    int r = 0;
    for (int i = 0; i < 9; ++i)
        for (int j = 0; j < 9; ++j)
            for (int k = 0; k < 9; ++k) {
                bool lt1 = (i < j) || (i == j && (j < k || (j == k && k < i)));
                bool lt2 = (i < k) || (i == k && (j < i || (j == i && k < j)));
                if (lt1 && lt2) { t.col[(i*9+j)*9+k] = (short)(45 + r); ++r; }
            }
    return t;
}
static constexpr Tbl3 TBL3 = make_tbl3();

// ============================================================================
// sig: SPLIT-CHEN version. Each 60-step window = A-half (seed + 29 diffs,
// waves 0-2) and B-half (30 diffs from zero state, waves 3-5) computed
// concurrently, merged with Chen's identity:
//   S1 = S1a+S1b;  S2[i][j] = S2a+S2b+S1a[i]S1b[j];
//   S3[i][j][k] = S3a+S3b + S1a[i]S2b[j][k] + S2a[i][j]S1b[k]
// Serial dep-chain per wave halves (60->30 steps); wave count doubles.
// Thread owns (i=ci, j=R in its 3 slabs, all k) of S2/S3 — identical
// slab layout to the step recurrence, so the merge is elementwise FMA.
// ============================================================================
#define SIG_STEP(VA_,VB_,VC_) { \
    const float hh = 0.5f * S1i + vi * (1.0f/6.0f); \
    const float ra = S2ra + hh * (VA_); \
    const float rb = S2rb + hh * (VB_); \
    const float rc = S2rc + hh * (VC_); \
    const f32x2 ra2 = {ra, ra}, rb2 = {rb, rb}, rc2 = {rc, rc}; \
    S3sa += ra * v0; S3pa0 += ra2*vp0; S3pa1 += ra2*vp1; S3pa2 += ra2*vp2; S3pa3 += ra2*vp3; \
    S3sb += rb * v0; S3pb0 += rb2*vp0; S3pb1 += rb2*vp1; S3pb2 += rb2*vp2; S3pb3 += rb2*vp3; \
    S3sc += rc * v0; S3pc0 += rc2*vp0; S3pc1 += rc2*vp1; S3pc2 += rc2*vp2; S3pc3 += rc2*vp3; \
    const float aa = S1i + 0.5f * vi; \
    S2ra += aa * (VA_); S2rb += aa * (VB_); S2rc += aa * (VC_); \
    S1i += vi; }

#define SIG_DIFFS(NITER, VA_,VB_,VC_) { \
    float4 d0 = *(const float4*)pd; \
    float4 d1 = *(const float4*)(pd + 4); \
    float rn = pd[ioff]; \
    _Pragma("unroll 2") \
    for (int j = 0; j < (NITER); ++j) { \
      const float4 e0 = d0; const float4 e1 = d1; const float rs = rn; \
      pd += 8; \
      d0 = *(const float4*)pd; d1 = *(const float4*)(pd + 4); rn = pd[ioff]; \
      const float v0 = DT; \
      const f32x2 vp0 = {e0.x, e0.y}, vp1 = {e0.z, e0.w}, vp2 = {e1.x, e1.y}, vp3 = {e1.z, e1.w}; \
      const float vi = (ci == 0) ? DT : rs; \
      SIG_STEP(VA_,VB_,VC_) \
    } }

#define SIG_MAIN_A(VA_,VB_,VC_) { \
    { const float* xr = &X[(g0 - lo) * 8]; \
      const float4 e0 = *(const float4*)xr; \
      const float4 e1 = *(const float4*)(xr + 4); \
      const float rs = xr[ioff]; \
      const float v0 = 0.0f; \
      const f32x2 vp0 = {e0.x, e0.y}, vp1 = {e0.z, e0.w}, vp2 = {e1.x, e1.y}, vp3 = {e1.z, e1.w}; \
      const float vi = (ci == 0) ? 0.0f : rs; \
      SIG_STEP(VA_,VB_,VC_) } \
    const float* pd = &PD[(sm59 + 1 - lo + 59) * 8]; \
    SIG_DIFFS(29, VA_,VB_,VC_) }

#define SIG_MAIN_B(VA_,VB_,VC_) { \
    const float* pd = &PD[(sm59 + 30 - lo + 59) * 8]; \
    SIG_DIFFS(30, VA_,VB_,VC_) }

// B-half store: S1b, S2b rows, S3b slabs (padded [R][10]: p0 at 0, pairs at 2/4/6/8)
#define SIG_STB(RA,RB,RC) \
    if (act) { \
        if ((RA) == 0) S1B[widx * 9 + ci] = S1i; \
        float* sb = &S2B[widx * 81 + ci * 9]; \
        sb[RA] = S2ra; sb[RB] = S2rb; sb[RC] = S2rc; \
        float* s3 = &S3B[widx * 810 + ci * 90]; \
        s3[(RA)*10] = S3sa; *(f32x2*)(s3+(RA)*10+2) = S3pa0; *(f32x2*)(s3+(RA)*10+4) = S3pa1; \
        *(f32x2*)(s3+(RA)*10+6) = S3pa2; *(f32x2*)(s3+(RA)*10+8) = S3pa3; \
        s3[(RB)*10] = S3sb; *(f32x2*)(s3+(RB)*10+2) = S3pb0; *(f32x2*)(s3+(RB)*10+4) = S3pb1; \
        *(f32x2*)(s3+(RB)*10+6) = S3pb2; *(f32x2*)(s3+(RB)*10+8) = S3pb3; \
        s3[(RC)*10] = S3sc; *(f32x2*)(s3+(RC)*10+2) = S3pc0; *(f32x2*)(s3+(RC)*10+4) = S3pc1; \
        *(f32x2*)(s3+(RC)*10+6) = S3pc2; *(f32x2*)(s3+(RC)*10+8) = S3pc3; \
    }

// A-half Chen combine for one slab (uses OLD S1i=S1a[ci], OLD S2r=S2a[ci][R])
#define SIG_CMB(SL,R) { \
    const float* bb  = s3b + (R)*10; \
    const float* s2r = s2b + (R)*9; \
    const f32x2 sr2 = {S2r##SL, S2r##SL}; \
    S3s##SL   += bb[0] + S1i * s2r[0] + S2r##SL * s1b[0]; \
    S3p##SL##0 += *(const f32x2*)(bb+2) + s1i2*mk2(s2r[1],s2r[2]) + sr2*sbp0; \
    S3p##SL##1 += *(const f32x2*)(bb+4) + s1i2*mk2(s2r[3],s2r[4]) + sr2*sbp1; \
    S3p##SL##2 += *(const f32x2*)(bb+6) + s1i2*mk2(s2r[5],s2r[6]) + sr2*sbp2; \
    S3p##SL##3 += *(const f32x2*)(bb+8) + s1i2*mk2(s2r[7],s2r[8]) + sr2*sbp3; }

#define SIG_COMBINE(RA,RB,RC) { \
    const float* s1b = &S1B[widx * 9]; \
    const float* s2b = &S2B[widx * 81]; \
    const float* s3b = &S3B[widx * 810 + ci * 90]; \
    const f32x2 s1i2 = {S1i, S1i}; \
    const f32x2 sbp0 = mk2(s1b[1], s1b[2]), sbp1 = mk2(s1b[3], s1b[4]); \
    const f32x2 sbp2 = mk2(s1b[5], s1b[6]), sbp3 = mk2(s1b[7], s1b[8]); \
    SIG_CMB(a,RA) SIG_CMB(b,RB) SIG_CMB(c,RC) \
    const float nS2a = S2ra + s2b[ci*9+(RA)] + S1i * s1b[RA]; \
    const float nS2b = S2rb + s2b[ci*9+(RB)] + S1i * s1b[RB]; \
    const float nS2c = S2rc + s2b[ci*9+(RC)] + S1i * s1b[RC]; \
    S2ra = nS2a; S2rb = nS2b; S2rc = nS2c; \
    S1i += s1b[ci]; \
    if (act) { \
        if ((RA) == 0) S1F[widx * 9 + ci] = S1i; \
        float* sf = &S2F[widx * 81 + ci * 9]; \
        sf[RA] = S2ra; sf[RB] = S2rb; sf[RC] = S2rc; \
    } }

#define S3EL0(SL) S3s##SL
#define S3EL1(SL) S3p##SL##0[0]
#define S3EL2(SL) S3p##SL##0[1]
#define S3EL3(SL) S3p##SL##1[0]
#define S3EL4(SL) S3p##SL##1[1]
#define S3EL5(SL) S3p##SL##2[0]
#define S3EL6(SL) S3p##SL##2[1]
#define S3EL7(SL) S3p##SL##3[0]
#define S3EL8(SL) S3p##SL##3[1]

#define SIG_E2(SL,J2) if (ci < (J2)) { \
    const float val2 = S2r##SL - 0.5f * S1i * s1v##J2; \
    const int col2 = 9 + ci*8 - (ci*(ci-1))/2 + ((J2) - ci - 1); \
    frow[col2] = __float2bfloat16(val2); }

#define SIG_E3(SL,R,K) { const int col3 = TBL3.col[tb + (R)*9 + (K)]; \
    if (col3 >= 0) { \
        const float val3 = S3EL##K(SL) \
            - 0.5f * (S1i * S2w[(R)*9+(K)] + S2r##SL * s1v##K) \
            + S1i * s1v##R * s1v##K * (1.0f/3.0f); \
        frow[col3] = __float2bfloat16(val3); } }

#define SIG_E3R(SL,R) SIG_E3(SL,R,0) SIG_E3(SL,R,1) SIG_E3(SL,R,2) SIG_E3(SL,R,3) \
    SIG_E3(SL,R,4) SIG_E3(SL,R,5) SIG_E3(SL,R,6) SIG_E3(SL,R,7) SIG_E3(SL,R,8)

#define SIG_EMIT(RA,RB,RC) \
    if (act) { \
        if ((RA) == 0) { \
            frow[ci] = __float2bfloat16(S1i); \
            if (ci == 0) { \
                const __hip_bfloat16 z16 = __float2bfloat16(0.0f); \
                frow[285] = z16; frow[286] = z16; frow[287] = z16; \
            } \
        } \
        SIG_E2(a,RA) SIG_E2(b,RB) SIG_E2(c,RC) \
        SIG_E3R(a,RA) SIG_E3R(b,RB) SIG_E3R(c,RC) \
    }

__global__ __launch_bounds__(384)
void sig_kernel(const float* __restrict__ x, __hip_bfloat16* __restrict__ feats) {
    __shared__ __align__(16) float X[66 * 8];
    __shared__ __align__(16) float PD[126 * 8];   // rows 0..58 zero pad, 59+r = x[lo+r]-x[lo+r-1]
    __shared__ float S2B[WPB * 81];
    __shared__ float S1B[WPB * 9];
    __shared__ float S2F[WPB * 81];
    __shared__ float S1F[WPB * 9];
    __shared__ __align__(16) float S3B[WPB * 810];

    const int blk = blockIdx.x;
    const int b   = blk / SBLK;
    const int s0  = (blk % SBLK) * WPB;
    const int lo  = (s0 - 59 > 0) ? (s0 - 59) : 0;
    const int hi  = (s0 + WPB - 1 < NS - 1) ? (s0 + WPB - 1) : (NS - 1);
    const int nrow = hi - lo + 1;     // <= 66
    const int tid = threadIdx.x;

    {   // stage x rows
        const float4* src = (const float4*)(x + ((size_t)b * NS + lo) * 8);
        float4* X4 = (float4*)X;
        const int n4 = nrow * 2;
        for (int t = tid; t < n4; t += 384) X4[t] = src[t];
    }
    __syncthreads();
    {   // build padded diff rows
        const float4* X4 = (const float4*)X;
        float4* PD4 = (float4*)PD;
        for (int t = tid; t < 252; t += 384) {
            const int p = t >> 1;         // padded row
            const int r = p - 59;         // diff row
            float4 dv = {0.f, 0.f, 0.f, 0.f};
            if (r > 0 && r < nrow) {
                const float4 a = X4[t - 118], bb = X4[t - 120];
                dv.x = a.x - bb.x; dv.y = a.y - bb.y; dv.z = a.z - bb.z; dv.w = a.w - bb.w;
            }
            PD4[t] = dv;
        }
    }
    __syncthreads();

    const int wav   = tid >> 6;           // 0..5
    const int hB    = (wav >= 3);         // 0 = A-half (steps 0..29), 1 = B-half (30..59)
    const int t3    = hB ? (wav - 3) : wav;   // slab third: rows {0,1,2}/{3,4,5}/{6,7,8}
    const int lt    = tid & 63;
    const int widx0 = lt / 9;             // 0..7 (lane 63 idle)
    const int ci    = lt - widx0 * 9;     // slab index 0..8
    const bool act  = (lt < 63) && (s0 + widx0 < NS);
    const int widx  = (widx0 < WPB - 1) ? widx0 : WPB - 1;
    int s = s0 + widx; if (s > NS - 1) s = NS - 1;

    float S3sa=0.f, S3sb=0.f, S3sc=0.f;
    f32x2 S3pa0={0.f,0.f},S3pa1={0.f,0.f},S3pa2={0.f,0.f},S3pa3={0.f,0.f};
    f32x2 S3pb0={0.f,0.f},S3pb1={0.f,0.f},S3pb2={0.f,0.f},S3pb3={0.f,0.f};
    f32x2 S3pc0={0.f,0.f},S3pc1={0.f,0.f},S3pc2={0.f,0.f},S3pc3={0.f,0.f};
    float S2ra=0.f, S2rb=0.f, S2rc=0.f;
    float S1i = 0.f;
    const int ioff = (ci > 0) ? (ci - 1) : 0;
    const int sm59 = s - 59;
    const int g0   = (sm59 > 0) ? sm59 : 0;
    const float DT = 1.0f / 59.0f;

    if (!hB) {
        if (t3 == 0)      { SIG_MAIN_A(v0,   e0.x, e0.y) }
        else if (t3 == 1) { SIG_MAIN_A(e0.z, e0.w, e1.x) }
        else              { SIG_MAIN_A(e1.y, e1.z, e1.w) }
    } else {
        if (t3 == 0)      { SIG_MAIN_B(v0,   e0.x, e0.y) }
        else if (t3 == 1) { SIG_MAIN_B(e0.z, e0.w, e1.x) }
        else              { SIG_MAIN_B(e1.y, e1.z, e1.w) }
        if (t3 == 0)      { SIG_STB(0,1,2) }
        else if (t3 == 1) { SIG_STB(3,4,5) }
        else              { SIG_STB(6,7,8) }
    }
    __syncthreads();

    if (!hB) {
        if (t3 == 0)      { SIG_COMBINE(0,1,2) }
        else if (t3 == 1) { SIG_COMBINE(3,4,5) }
        else              { SIG_COMBINE(6,7,8) }
    }
    __syncthreads();

    if (!hB) {
        const float* s1p = &S1F[widx * 9];
        const float s1v0=s1p[0], s1v1=s1p[1], s1v2=s1p[2], s1v3=s1p[3], s1v4=s1p[4];
        const float s1v5=s1p[5], s1v6=s1p[6], s1v7=s1p[7], s1v8=s1p[8];
        const float* S2w = &S2F[widx * 81];
        const int tb = ci * 81;
        __hip_bfloat16* frow = feats + (size_t)(b * NS + s) * KPAD;

        if (t3 == 0)      { SIG_EMIT(0,1,2) }
        else if (t3 == 1) { SIG_EMIT(3,4,5) }
        else              { SIG_EMIT(6,7,8) }
    }
}

// ============================================================================
// prep: fused convert_w1 + convert_w2g + stats-zero (r1 version, reverted)
// ============================================================================
__global__ __launch_bounds__(512)
void prep_kernel(const float* __restrict__ w1, const float* __restrict__ w2,
                 const float* __restrict__ lng, const float* __restrict__ lnb,
                 const float* __restrict__ b2,
                 __hip_bfloat16* __restrict__ w1T, __hip_bfloat16* __restrict__ w2g,
                 float* __restrict__ gw, float* __restrict__ cvec,
                 float* __restrict__ stats) {
    const int blk = blockIdx.x;
    if (blk < 256) {
        const int n = blk, k = threadIdx.x;
        const float wv = w2[(size_t)k * HID + n];
        const float a = lng[k] * wv;
        const float c = lnb[k] * wv;
        w2g[(size_t)n * H2 + k] = __float2bfloat16(a);
        float ra = a, rc = c;
#pragma unroll
        for (int d = 1; d < 64; d <<= 1) { ra += __shfl_xor(ra, d); rc += __shfl_xor(rc, d); }
        __shared__ float r1[8], r2[8];
        const int wv_ = k >> 6, ln = k & 63;
        if (ln == 0) { r1[wv_] = ra; r2[wv_] = rc; }
        __syncthreads();
        if (k == 0) {
            float sa = 0.f, sc = 0.f;
#pragma unroll
            for (int i = 0; i < 8; ++i) { sa += r1[i]; sc += r2[i]; }
            gw[n] = sa; cvec[n] = sc + b2[n];
        }
    } else {
        const int n = blk - 256;           // 0..511
        const int k = threadIdx.x;
        if (k < KPAD) {
            const float v = (k < 285) ? w1[(size_t)k * H2 + n] : 0.0f;
            w1T[(size_t)n * KPAD + k] = __float2bfloat16(v);
        }
        if (k < 64) stats[n * 64 + k] = 0.0f;   // 512*64 = 32768 floats
    }
}

// ============================================================================
// GEMM core (r1 version, reverted — measured best): 128x128 tile, 256 thr,
// 2-phase double-buffered LDS staging.
// ============================================================================
#define GDECL \
    f32x4 acc00={0,0,0,0},acc01={0,0,0,0},acc02={0,0,0,0},acc03={0,0,0,0}; \
    f32x4 acc10={0,0,0,0},acc11={0,0,0,0},acc12={0,0,0,0},acc13={0,0,0,0}; \
    f32x4 acc20={0,0,0,0},acc21={0,0,0,0},acc22={0,0,0,0},acc23={0,0,0,0}; \
    f32x4 acc30={0,0,0,0},acc31={0,0,0,0},acc32={0,0,0,0},acc33={0,0,0,0};

#define GMROW(mf) { const short8 av = *(const short8*)(abase + (mf)*512); \
    acc##mf##0 = MFMA(av, b0v, acc##mf##0); acc##mf##1 = MFMA(av, b1v, acc##mf##1); \
    acc##mf##2 = MFMA(av, b2v, acc##mf##2); acc##mf##3 = MFMA(av, b3v, acc##mf##3); }

#define GSTAGE(APTR, BPTR, KD, K0, LA, LB) { \
    int c = tid; \
    gl2lds16((APTR) + (size_t)(m0 + (c>>2))*(KD) + (K0) + (c&3)*8, (char*)(LA) + (c & ~63)*16); \
    gl2lds16((BPTR) + (size_t)(n0 + (c>>2))*(KD) + (K0) + (c&3)*8, (char*)(LB) + (c & ~63)*16); \
    c = tid + 256; \
    gl2lds16((APTR) + (size_t)(m0 + (c>>2))*(KD) + (K0) + (c&3)*8, (char*)(LA) + (c & ~63)*16); \
    gl2lds16((BPTR) + (size_t)(n0 + (c>>2))*(KD) + (K0) + (c&3)*8, (char*)(LB) + (c & ~63)*16); }

#define GCOMP(LA, LB) { \
    const __hip_bfloat16* abase = (LA) + (mh + l16)*32 + quad*8; \
    const __hip_bfloat16* bbase = (LB) + (nh + l16)*32 + quad*8; \
    const short8 b0v = *(const short8*)(bbase); \
    const short8 b1v = *(const short8*)(bbase + 512); \
    const short8 b2v = *(const short8*)(bbase + 1024); \
    const short8 b3v = *(const short8*)(bbase + 1536); \
    GMROW(0) GMROW(1) GMROW(2) GMROW(3) }

#define GEMM_PIPE(APTR, BPTR, KD, KSTEPS) \
    GSTAGE(APTR, BPTR, KD, 0, ldsA0, ldsB0) \
    __syncthreads(); \
    _Pragma("unroll 1") \
    for (int kt = 0; kt < (KSTEPS); kt += 2) { \
        if (kt + 1 < (KSTEPS)) { GSTAGE(APTR, BPTR, KD, (kt+1)*32, ldsA1, ldsB1) } \
        GCOMP(ldsA0, ldsB0) \
        __syncthreads(); \
        if (kt + 1 < (KSTEPS)) { \
            if (kt + 2 < (KSTEPS)) { GSTAGE(APTR, BPTR, KD, (kt+2)*32, ldsA0, ldsB0) } \
            GCOMP(ldsA1, ldsB1) \
            __syncthreads(); \
        } \
    }

// GEMM1: h1 = GELU(feats @ w1 + b1) -> bf16, plus per-row (sum, sumsq) atomics.
#define G1EP(mf,nf) { \
    const int colv = n0 + nh + (nf)*16 + l16; \
    const float bv = bias[colv]; \
    f32x4 e; \
    e[0] = geluf(acc##mf##nf[0] + bv); e[1] = geluf(acc##mf##nf[1] + bv); \
    e[2] = geluf(acc##mf##nf[2] + bv); e[3] = geluf(acc##mf##nf[3] + bv); \
    const int rrow = m0 + mh + (mf)*16 + quad*4; \
    h1[(size_t)(rrow+0)*H2 + colv] = __float2bfloat16(e[0]); \
    h1[(size_t)(rrow+1)*H2 + colv] = __float2bfloat16(e[1]); \
    h1[(size_t)(rrow+2)*H2 + colv] = __float2bfloat16(e[2]); \
    h1[(size_t)(rrow+3)*H2 + colv] = __float2bfloat16(e[3]); \
    sum##mf += e; sq##mf += e*e; }

#define G1RED(mf) { \
    f32x4 s = sum##mf, q = sq##mf; \
    s += shfl4(s,1); q += shfl4(q,1); s += shfl4(s,2); q += shfl4(q,2); \
    s += shfl4(s,4); q += shfl4(q,4); s += shfl4(s,8); q += shfl4(q,8); \
    if (l16 == 0) { const int rrow = m0 + mh + (mf)*16 + quad*4; \
        atomicAdd(&stats[2*(rrow+0)],   s[0]); atomicAdd(&stats[2*(rrow+0)+1], q[0]); \
        atomicAdd(&stats[2*(rrow+1)],   s[1]); atomicAdd(&stats[2*(rrow+1)+1], q[1]); \
        atomicAdd(&stats[2*(rrow+2)],   s[2]); atomicAdd(&stats[2*(rrow+2)+1], q[2]); \
        atomicAdd(&stats[2*(rrow+3)],   s[3]); atomicAdd(&stats[2*(rrow+3)+1], q[3]); } }

__global__ __launch_bounds__(256) __attribute__((amdgpu_waves_per_eu(1, 4)))
void gemm1_kernel(const __hip_bfloat16* __restrict__ feats,
                  const __hip_bfloat16* __restrict__ w1T,
                  const float* __restrict__ bias,
                  __hip_bfloat16* __restrict__ h1,
                  float* __restrict__ stats) {
    __shared__ __align__(16) __hip_bfloat16 ldsA0[128 * 32];
    __shared__ __align__(16) __hip_bfloat16 ldsB0[128 * 32];
    __shared__ __align__(16) __hip_bfloat16 ldsA1[128 * 32];
    __shared__ __align__(16) __hip_bfloat16 ldsB1[128 * 32];
    const int tid  = threadIdx.x;
    const int wave = tid >> 6;
    const int lane = tid & 63;
    const int quad = lane >> 4;
    const int l16  = lane & 15;
    const int mh   = (wave >> 1) * 64;
    const int nh   = (wave & 1) * 64;
    const int m0   = blockIdx.x * 128;
    const int n0   = blockIdx.y * 128;
    GDECL
    GEMM_PIPE(feats, w1T, KPAD, 9)
    f32x4 sum0={0,0,0,0},sum1={0,0,0,0},sum2={0,0,0,0},sum3={0,0,0,0};
    f32x4 sq0={0,0,0,0},sq1={0,0,0,0},sq2={0,0,0,0},sq3={0,0,0,0};
    G1EP(0,0) G1EP(0,1) G1EP(0,2) G1EP(0,3)
    G1EP(1,0) G1EP(1,1) G1EP(1,2) G1EP(1,3)
    G1EP(2,0) G1EP(2,1) G1EP(2,2) G1EP(2,3)
    G1EP(3,0) G1EP(3,1) G1EP(3,2) G1EP(3,3)
    G1RED(0) G1RED(1) G1RED(2) G1RED(3)
}

// GEMM2: out = rstd_m*(h1 @ w2g - mu_m*gw[n]) + cvec[n]  (LN folded)
#define STATR(r) { const float su = stats[2*(rrow+(r))]; const float qu = stats[2*(rrow+(r))+1]; \
    const float m_ = su * (1.0f/512.0f); const float v_ = qu * (1.0f/512.0f) - m_*m_; \
    muv[r] = m_; rsv[r] = rsqrtf(v_ + 1e-5f); }

#define G2C(mf,nf) { const int colv = n0 + nh + (nf)*16 + l16; \
    const float g_ = gw[colv], c_ = cvec[colv]; \
    out[(size_t)(rrow+0)*HID + colv] = rsv[0]*(acc##mf##nf[0] - muv[0]*g_) + c_; \
    out[(size_t)(rrow+1)*HID + colv] = rsv[1]*(acc##mf##nf[1] - muv[1]*g_) + c_; \
    out[(size_t)(rrow+2)*HID + colv] = rsv[2]*(acc##mf##nf[2] - muv[2]*g_) + c_; \
    out[(size_t)(rrow+3)*HID + colv] = rsv[3]*(acc##mf##nf[3] - muv[3]*g_) + c_; }

#define G2EP(mf) { const int rrow = m0 + mh + (mf)*16 + quad*4; \
    f32x4 muv, rsv; \
    STATR(0) STATR(1) STATR(2) STATR(3) \
    G2C(mf,0) G2C(mf,1) G2C(mf,2) G2C(mf,3) }

__global__ __launch_bounds__(256) __attribute__((amdgpu_waves_per_eu(1, 4)))
void gemm2_kernel(const __hip_bfloat16* __restrict__ h1,
                  const __hip_bfloat16* __restrict__ w2g,
                  const float* __restrict__ stats,
                  const float* __restrict__ gw,
                  const float* __restrict__ cvec,
                  float* __restrict__ out) {
    __shared__ __align__(16) __hip_bfloat16 ldsA0[128 * 32];
    __shared__ __align__(16) __hip_bfloat16 ldsB0[128 * 32];
    __shared__ __align__(16) __hip_bfloat16 ldsA1[128 * 32];
    __shared__ __align__(16) __hip_bfloat16 ldsB1[128 * 32];
    const int tid  = threadIdx.x;
    const int wave = tid >> 6;
    const int lane = tid & 63;
    const int quad = lane >> 4;
    const int l16  = lane & 15;
    const int mh   = (wave >> 1) * 64;
    const int nh   = (wave & 1) * 64;
    const int m0   = blockIdx.x * 128;
    const int n0   = blockIdx.y * 128;
    GDECL
    GEMM_PIPE(h1, w2g, H2, 16)
    G2EP(0) G2EP(1) G2EP(2) G2EP(3)
}

// ============================================================================
extern "C" void kernel_launch(void* const* d_in, const int* in_sizes, int n_in,
                              void* d_out, int out_size, void* d_ws, size_t ws_size,
                              hipStream_t stream) {
    const float* x   = (const float*)d_in[0];
    const float* w1  = (const float*)d_in[1];
    const float* b1  = (const float*)d_in[2];
    const float* lng = (const float*)d_in[3];
    const float* lnb = (const float*)d_in[4];
    const float* w2  = (const float*)d_in[5];
    const float* b2  = (const float*)d_in[6];
    float* out = (float*)d_out;

    char* ws = (char*)d_ws;
    __hip_bfloat16* feats = (__hip_bfloat16*)(ws);                        // 9437184
    __hip_bfloat16* h1    = (__hip_bfloat16*)(ws + 9437184);              // 16777216
    __hip_bfloat16* w1T   = (__hip_bfloat16*)(ws + 26214400);             // 294912
    __hip_bfloat16* w2g   = (__hip_bfloat16*)(ws + 26509312);             // 262144
    float*          gw    = (float*)(ws + 26771456);                      // 4096
    float*          cvec  = (float*)(ws + 26775552);                      // 4096
    float*          stats = (float*)(ws + 26779648);                      // 131072

    prep_kernel<<<dim3(768), dim3(512), 0, stream>>>(w1, w2, lng, lnb, b2,
                                                     w1T, w2g, gw, cvec, stats);
    sig_kernel<<<dim3(8 * SBLK), dim3(384), 0, stream>>>(x, feats);
    gemm1_kernel<<<dim3(128, 4), dim3(256), 0, stream>>>(feats, w1T, b1, h1, stats);
    gemm2_kernel<<<dim3(128, 2), dim3(256), 0, stream>>>(h1, w2g, stats, gw, cvec, out);
}

// Round 4
// 149.776 us; speedup vs baseline: 1.1319x; 1.1261x over previous
//
#include <hip/hip_runtime.h>
#include <hip/hip_bf16.h>
#include <cstdint>
#include <cstddef>

typedef short short8 __attribute__((ext_vector_type(8)));
typedef float f32x4 __attribute__((ext_vector_type(4)));
typedef float f32x2 __attribute__((ext_vector_type(2)));

#define NS    2048
#define KPAD  288
#define H2    512
#define HID   256
#define WPB   7       // windows per sig workgroup (192 thr = 3 waves = 3 thirds)
#define SBLK  293     // ceil(2048/7)

#define MFMA(a,b,c) __builtin_amdgcn_mfma_f32_16x16x32_bf16((a),(b),(c),0,0,0)

__device__ __forceinline__ void gl2lds16(const void* g, void* l) {
    __builtin_amdgcn_global_load_lds(
        (const __attribute__((address_space(1))) void*)g,
        (__attribute__((address_space(3))) void*)l, 16, 0, 0);
}
__device__ __forceinline__ float geluf(float x) {
    return 0.5f * x * (1.0f + erff(x * 0.70710678118654752f));
}
__device__ __forceinline__ f32x4 shfl4(f32x4 v, int d) {
    f32x4 r;
    r[0] = __shfl_xor(v[0], d); r[1] = __shfl_xor(v[1], d);
    r[2] = __shfl_xor(v[2], d); r[3] = __shfl_xor(v[3], d);
    return r;
}

struct Tbl3 { short col[729]; };
static constexpr Tbl3 make_tbl3() {
    Tbl3 t{};
    for (int x = 0; x < 729; ++x) t.col[x] = -1;
    int r = 0;
    for (int i = 0; i < 9; ++i)
        for (int j = 0; j < 9; ++j)
            for (int k = 0; k < 9; ++k) {
                bool lt1 = (i < j) || (i == j && (j < k || (j == k && k < i)));
                bool lt2 = (i < k) || (i == k && (j < i || (j == i && k < j)));
                if (lt1 && lt2) { t.col[(i*9+j)*9+k] = (short)(45 + r); ++r; }
            }
    return t;
}
static constexpr Tbl3 TBL3 = make_tbl3();

// ============================================================================
// sig: r1 version verbatim (measured 48.2us; r3 split-Chen regressed to 61.5).
// ============================================================================
#define SIG_STEP(VA_,VB_,VC_) { \
    const float hh = 0.5f * S1i + vi * (1.0f/6.0f); \
    const float ra = S2ra + hh * (VA_); \
    const float rb = S2rb + hh * (VB_); \
    const float rc = S2rc + hh * (VC_); \
    const f32x2 ra2 = {ra, ra}, rb2 = {rb, rb}, rc2 = {rc, rc}; \
    S3sa += ra * v0; S3pa0 += ra2*vp0; S3pa1 += ra2*vp1; S3pa2 += ra2*vp2; S3pa3 += ra2*vp3; \
    S3sb += rb * v0; S3pb0 += rb2*vp0; S3pb1 += rb2*vp1; S3pb2 += rb2*vp2; S3pb3 += rb2*vp3; \
    S3sc += rc * v0; S3pc0 += rc2*vp0; S3pc1 += rc2*vp1; S3pc2 += rc2*vp2; S3pc3 += rc2*vp3; \
    const float aa = S1i + 0.5f * vi; \
    S2ra += aa * (VA_); S2rb += aa * (VB_); S2rc += aa * (VC_); \
    S1i += vi; }

#define SIG_MAIN(VA_,VB_,VC_) { \
    { const float* xr = &X[(g0 - lo) * 8]; \
      const float4 e0 = *(const float4*)xr; \
      const float4 e1 = *(const float4*)(xr + 4); \
      const float rs = xr[ioff]; \
      const float v0 = 0.0f; \
      const f32x2 vp0 = {e0.x, e0.y}, vp1 = {e0.z, e0.w}, vp2 = {e1.x, e1.y}, vp3 = {e1.z, e1.w}; \
      const float vi = (ci == 0) ? 0.0f : rs; \
      SIG_STEP(VA_,VB_,VC_) } \
    const float* pd = &PD[(sm59 + 1 - lo + 59) * 8]; \
    float4 d0 = *(const float4*)pd; \
    float4 d1 = *(const float4*)(pd + 4); \
    float rn = pd[ioff]; \
    _Pragma("unroll 2") \
    for (int j = 1; j < 60; ++j) { \
      const float4 e0 = d0; const float4 e1 = d1; const float rs = rn; \
      pd += 8; \
      d0 = *(const float4*)pd; d1 = *(const float4*)(pd + 4); rn = pd[ioff]; \
      const float v0 = DT; \
      const f32x2 vp0 = {e0.x, e0.y}, vp1 = {e0.z, e0.w}, vp2 = {e1.x, e1.y}, vp3 = {e1.z, e1.w}; \
      const float vi = (ci == 0) ? DT : rs; \
      SIG_STEP(VA_,VB_,VC_) \
    } }

#define SIG_ST(RA,RB,RC) \
    if (act) { \
        if ((RA) == 0) S1buf[widx * 9 + ci] = S1i; \
        float* sb = &S2buf[widx * 81 + ci * 9]; \
        sb[RA] = S2ra; sb[RB] = S2rb; sb[RC] = S2rc; \
    }

#define S3EL0(SL) S3s##SL
#define S3EL1(SL) S3p##SL##0[0]
#define S3EL2(SL) S3p##SL##0[1]
#define S3EL3(SL) S3p##SL##1[0]
#define S3EL4(SL) S3p##SL##1[1]
#define S3EL5(SL) S3p##SL##2[0]
#define S3EL6(SL) S3p##SL##2[1]
#define S3EL7(SL) S3p##SL##3[0]
#define S3EL8(SL) S3p##SL##3[1]

#define SIG_E2(SL,J2) if (ci < (J2)) { \
    const float val2 = S2r##SL - 0.5f * S1i * s1v##J2; \
    const int col2 = 9 + ci*8 - (ci*(ci-1))/2 + ((J2) - ci - 1); \
    frow[col2] = __float2bfloat16(val2); }

#define SIG_E3(SL,R,K) { const int col3 = TBL3.col[tb + (R)*9 + (K)]; \
    if (col3 >= 0) { \
        const float val3 = S3EL##K(SL) \
            - 0.5f * (S1i * S2w[(R)*9+(K)] + S2r##SL * s1v##K) \
            + S1i * s1v##R * s1v##K * (1.0f/3.0f); \
        frow[col3] = __float2bfloat16(val3); } }

#define SIG_E3R(SL,R) SIG_E3(SL,R,0) SIG_E3(SL,R,1) SIG_E3(SL,R,2) SIG_E3(SL,R,3) \
    SIG_E3(SL,R,4) SIG_E3(SL,R,5) SIG_E3(SL,R,6) SIG_E3(SL,R,7) SIG_E3(SL,R,8)

#define SIG_EMIT(RA,RB,RC) \
    if (act) { \
        if ((RA) == 0) { \
            frow[ci] = __float2bfloat16(S1i); \
            if (ci == 0) { \
                const __hip_bfloat16 z16 = __float2bfloat16(0.0f); \
                frow[285] = z16; frow[286] = z16; frow[287] = z16; \
            } \
        } \
        SIG_E2(a,RA) SIG_E2(b,RB) SIG_E2(c,RC) \
        SIG_E3R(a,RA) SIG_E3R(b,RB) SIG_E3R(c,RC) \
    }

__global__ __launch_bounds__(192) __attribute__((amdgpu_waves_per_eu(1, 6)))
void sig_kernel(const float* __restrict__ x, __hip_bfloat16* __restrict__ feats) {
    __shared__ __align__(16) float X[66 * 8];
    __shared__ __align__(16) float PD[126 * 8];   // rows 0..58 zero pad, 59+r = x[lo+r]-x[lo+r-1]
    __shared__ float S2buf[WPB * 81];
    __shared__ float S1buf[WPB * 9];

    const int blk = blockIdx.x;
    const int b   = blk / SBLK;
    const int s0  = (blk % SBLK) * WPB;
    const int lo  = (s0 - 59 > 0) ? (s0 - 59) : 0;
    const int hi  = (s0 + WPB - 1 < NS - 1) ? (s0 + WPB - 1) : (NS - 1);
    const int nrow = hi - lo + 1;     // <= 66
    const int tid = threadIdx.x;

    {   // stage x rows
        const float4* src = (const float4*)(x + ((size_t)b * NS + lo) * 8);
        float4* X4 = (float4*)X;
        const int n4 = nrow * 2;
        for (int t = tid; t < n4; t += 192) X4[t] = src[t];
    }
    __syncthreads();
    {   // build padded diff rows
        const float4* X4 = (const float4*)X;
        float4* PD4 = (float4*)PD;
        for (int t = tid; t < 252; t += 192) {
            const int p = t >> 1;         // padded row
            const int r = p - 59;         // diff row
            float4 dv = {0.f, 0.f, 0.f, 0.f};
            if (r > 0 && r < nrow) {
                const float4 a = X4[t - 118], bb = X4[t - 120];
                dv.x = a.x - bb.x; dv.y = a.y - bb.y; dv.z = a.z - bb.z; dv.w = a.w - bb.w;
            }
            PD4[t] = dv;
        }
    }
    __syncthreads();

    const int t3    = tid >> 6;           // third (wave-uniform): rows {0,1,2}/{3,4,5}/{6,7,8}
    const int lt    = tid & 63;
    const int widx0 = lt / 9;             // 0..7 (lane 63 idle)
    const int ci    = lt - widx0 * 9;     // slab index 0..8
    const bool act  = (lt < 63) && (s0 + widx0 < NS);
    const int widx  = (widx0 < WPB - 1) ? widx0 : WPB - 1;
    int s = s0 + widx; if (s > NS - 1) s = NS - 1;

    float S3sa=0.f, S3sb=0.f, S3sc=0.f;
    f32x2 S3pa0={0.f,0.f},S3pa1={0.f,0.f},S3pa2={0.f,0.f},S3pa3={0.f,0.f};
    f32x2 S3pb0={0.f,0.f},S3pb1={0.f,0.f},S3pb2={0.f,0.f},S3pb3={0.f,0.f};
    f32x2 S3pc0={0.f,0.f},S3pc1={0.f,0.f},S3pc2={0.f,0.f},S3pc3={0.f,0.f};
    float S2ra=0.f, S2rb=0.f, S2rc=0.f;
    float S1i = 0.f;
    const int ioff = (ci > 0) ? (ci - 1) : 0;
    const int sm59 = s - 59;
    const int g0   = (sm59 > 0) ? sm59 : 0;
    const float DT = 1.0f / 59.0f;

    if (t3 == 0)      { SIG_MAIN(v0,   e0.x, e0.y) }
    else if (t3 == 1) { SIG_MAIN(e0.z, e0.w, e1.x) }
    else              { SIG_MAIN(e1.y, e1.z, e1.w) }

    if (t3 == 0)      { SIG_ST(0,1,2) }
    else if (t3 == 1) { SIG_ST(3,4,5) }
    else              { SIG_ST(6,7,8) }
    __syncthreads();

    const float* s1p = &S1buf[widx * 9];
    const float s1v0=s1p[0], s1v1=s1p[1], s1v2=s1p[2], s1v3=s1p[3], s1v4=s1p[4];
    const float s1v5=s1p[5], s1v6=s1p[6], s1v7=s1p[7], s1v8=s1p[8];
    const float* S2w = &S2buf[widx * 81];
    const int tb = ci * 81;
    __hip_bfloat16* frow = feats + (size_t)(b * NS + s) * KPAD;

    if (t3 == 0)      { SIG_EMIT(0,1,2) }
    else if (t3 == 1) { SIG_EMIT(3,4,5) }
    else              { SIG_EMIT(6,7,8) }
}

// ============================================================================
// prep: fused convert_w1 + convert_w2g (stats no longer needed — LN is fused)
// ============================================================================
__global__ __launch_bounds__(512)
void prep_kernel(const float* __restrict__ w1, const float* __restrict__ w2,
                 const float* __restrict__ lng, const float* __restrict__ lnb,
                 const float* __restrict__ b2,
                 __hip_bfloat16* __restrict__ w1T, __hip_bfloat16* __restrict__ w2g,
                 float* __restrict__ gw, float* __restrict__ cvec) {
    const int blk = blockIdx.x;
    if (blk < 256) {
        const int n = blk, k = threadIdx.x;
        const float wv = w2[(size_t)k * HID + n];
        const float a = lng[k] * wv;
        const float c = lnb[k] * wv;
        w2g[(size_t)n * H2 + k] = __float2bfloat16(a);
        float ra = a, rc = c;
#pragma unroll
        for (int d = 1; d < 64; d <<= 1) { ra += __shfl_xor(ra, d); rc += __shfl_xor(rc, d); }
        __shared__ float r1[8], r2[8];
        const int wv_ = k >> 6, ln = k & 63;
        if (ln == 0) { r1[wv_] = ra; r2[wv_] = rc; }
        __syncthreads();
        if (k == 0) {
            float sa = 0.f, sc = 0.f;
#pragma unroll
            for (int i = 0; i < 8; ++i) { sa += r1[i]; sc += r2[i]; }
            gw[n] = sa; cvec[n] = sc + b2[n];
        }
    } else {
        const int n = blk - 256;           // 0..511
        const int k = threadIdx.x;
        if (k < KPAD) {
            const float v = (k < 285) ? w1[(size_t)k * H2 + n] : 0.0f;
            w1T[(size_t)n * KPAD + k] = __float2bfloat16(v);
        }
    }
}

// ============================================================================
// mlp_kernel: fused gemm1 + GELU + LN-stats + gemm2 + LN-epilogue.
// One 32-row strip per block; 512 blocks (2/CU by LDS: 69KB).
// - gemm1: 9 k-steps; w1T slices [512][32] (32KB) double-buffered between
//   Blds and Hbuf (Hbuf is free until h is produced); feats slices [32][32]
//   double-buffered in Ab0/Ab1.
// - h (GELU out, bf16-rounded) written to swizzled Hbuf; row (sum,sq) to LDS.
// - gemm2: 16 k-steps; w2g slices [256][32] (16KB) double-buffered in the
//   two halves of Blds; A read from Hbuf.
// - LN folded in final epilogue: out = rstd*(acc2 - mu*gw) + cvec.
// Swizzle family (both-sides involution, rule 21): a [R][32k] bf16 tile has
// 4 chunks of 16B per 64B row; staging pulls global chunk (q ^ ((row>>1)&3))
// into linear dest chunk q; reads use off = row*64 + ((quad^((l16>>1)&3))*16)
// -> 16 lanes spread over 8 bank-groups = 2-way (free). Hbuf [32][64ch]:
// chunk ^= (row&7) on both write (epilogue) and read (gemm2 A).
// ============================================================================
__global__ __launch_bounds__(256)
void mlp_kernel(const __hip_bfloat16* __restrict__ feats,
                const __hip_bfloat16* __restrict__ w1T,
                const float* __restrict__ bias,
                const __hip_bfloat16* __restrict__ w2g,
                const float* __restrict__ gw,
                const float* __restrict__ cvec,
                float* __restrict__ out) {
    __shared__ __align__(16) __hip_bfloat16 Blds[512 * 32];   // 32KB
    __shared__ __align__(16) __hip_bfloat16 Hbuf[32 * 512];   // 32KB (B-dbuf partner, then h)
    __shared__ __align__(16) __hip_bfloat16 Ab0[32 * 32];     // 2KB
    __shared__ __align__(16) __hip_bfloat16 Ab1[32 * 32];     // 2KB
    __shared__ float sstat[4][32][2];                          // 1KB

    const int tid  = threadIdx.x;
    const int wave = tid >> 6;
    const int lane = tid & 63;
    const int quad = lane >> 4;
    const int l16  = lane & 15;
    const int m0   = blockIdx.x * 32;
    const int swz16 = (quad ^ ((l16 >> 1) & 3)) * 16;   // read swizzle, all [R][32k] tiles

#define STAGE_B1(S, DST) { \
    _Pragma("unroll") \
    for (int i_ = 0; i_ < 8; ++i_) { \
        const int c_ = tid + i_ * 256; const int r_ = c_ >> 2; const int q_ = c_ & 3; \
        gl2lds16(w1T + (size_t)r_ * KPAD + (S) * 32 + ((q_ ^ ((r_ >> 1) & 3)) * 8), \
                 (char*)(DST) + (c_ & ~63) * 16); } }
#define STAGE_A(S, DST) { if (tid < 128) { \
        const int r_ = tid >> 2; const int q_ = tid & 3; \
        gl2lds16(feats + (size_t)(m0 + r_) * KPAD + (S) * 32 + ((q_ ^ ((r_ >> 1) & 3)) * 8), \
                 (char*)(DST) + (tid & ~63) * 16); } }
#define STAGE_B2(T, DST) { \
    _Pragma("unroll") \
    for (int i_ = 0; i_ < 4; ++i_) { \
        const int c_ = tid + i_ * 256; const int r_ = c_ >> 2; const int q_ = c_ & 3; \
        gl2lds16(w2g + (size_t)r_ * H2 + (T) * 32 + ((q_ ^ ((r_ >> 1) & 3)) * 8), \
                 (char*)(DST) + (c_ & ~63) * 16); } }

    // zero stats + prologue stage
    ((float*)sstat)[tid] = 0.0f;
    STAGE_B1(0, Blds)
    STAGE_A(0, Ab0)
    __syncthreads();

    // ---------------- GEMM1: 32x512, K=288 ----------------
    f32x4 a1[2][8];
#pragma unroll
    for (int mf = 0; mf < 2; ++mf)
#pragma unroll
        for (int nf = 0; nf < 8; ++nf) a1[mf][nf] = f32x4{0.f, 0.f, 0.f, 0.f};

#pragma unroll 1
    for (int s = 0; s < 9; ++s) {
        if (s < 8) {
            if ((s + 1) & 1) { STAGE_B1(s + 1, Hbuf) STAGE_A(s + 1, Ab1) }
            else             { STAGE_B1(s + 1, Blds) STAGE_A(s + 1, Ab0) }
        }
        const char* Ac = (s & 1) ? (const char*)Ab1 : (const char*)Ab0;
        const char* Bc = (s & 1) ? (const char*)Hbuf : (const char*)Blds;
        const short8 av0 = *(const short8*)(Ac + l16 * 64 + swz16);
        const short8 av1 = *(const short8*)(Ac + (16 + l16) * 64 + swz16);
#pragma unroll
        for (int nf = 0; nf < 8; ++nf) {
            const short8 bv = *(const short8*)(Bc + (size_t)(wave * 128 + nf * 16 + l16) * 64 + swz16);
            a1[0][nf] = MFMA(av0, bv, a1[0][nf]);
            a1[1][nf] = MFMA(av1, bv, a1[1][nf]);
        }
        __syncthreads();
    }

    // ---------------- GELU epilogue -> Hbuf (swizzled) + stats ----------------
    {
        f32x4 sum0 = {0,0,0,0}, sum1 = {0,0,0,0}, sq0 = {0,0,0,0}, sq1 = {0,0,0,0};
#pragma unroll
        for (int nf = 0; nf < 8; ++nf) {
            const int col = wave * 128 + nf * 16 + l16;
            const float bv = bias[col];
            f32x4 e0, e1;
#pragma unroll
            for (int r = 0; r < 4; ++r) { e0[r] = geluf(a1[0][nf][r] + bv); e1[r] = geluf(a1[1][nf][r] + bv); }
#pragma unroll
            for (int r = 0; r < 4; ++r) {
                const int row0 = quad * 4 + r;
                const int row1 = 16 + row0;
                const int ch0 = (col >> 3) ^ (row0 & 7);
                const int ch1 = (col >> 3) ^ (row1 & 7);
                *(__hip_bfloat16*)((char*)Hbuf + row0 * 1024 + ch0 * 16 + (col & 7) * 2) = __float2bfloat16(e0[r]);
                *(__hip_bfloat16*)((char*)Hbuf + row1 * 1024 + ch1 * 16 + (col & 7) * 2) = __float2bfloat16(e1[r]);
            }
            sum0 += e0; sq0 += e0 * e0; sum1 += e1; sq1 += e1 * e1;
        }
        sum0 += shfl4(sum0, 1); sq0 += shfl4(sq0, 1); sum1 += shfl4(sum1, 1); sq1 += shfl4(sq1, 1);
        sum0 += shfl4(sum0, 2); sq0 += shfl4(sq0, 2); sum1 += shfl4(sum1, 2); sq1 += shfl4(sq1, 2);
        sum0 += shfl4(sum0, 4); sq0 += shfl4(sq0, 4); sum1 += shfl4(sum1, 4); sq1 += shfl4(sq1, 4);
        sum0 += shfl4(sum0, 8); sq0 += shfl4(sq0, 8); sum1 += shfl4(sum1, 8); sq1 += shfl4(sq1, 8);
        if (l16 == 0) {
#pragma unroll
            for (int r = 0; r < 4; ++r) {
                sstat[wave][quad * 4 + r][0]      = sum0[r];
                sstat[wave][quad * 4 + r][1]      = sq0[r];
                sstat[wave][16 + quad * 4 + r][0] = sum1[r];
                sstat[wave][16 + quad * 4 + r][1] = sq1[r];
            }
        }
        __syncthreads();
    }

    // ---------------- GEMM2: 32x256, K=512, A from Hbuf ----------------
    f32x4 a2[2][4];
#pragma unroll
    for (int mf = 0; mf < 2; ++mf)
#pragma unroll
        for (int nf = 0; nf < 4; ++nf) a2[mf][nf] = f32x4{0.f, 0.f, 0.f, 0.f};

    STAGE_B2(0, Blds)
    __syncthreads();

    const int hsw = l16 & 7;
#pragma unroll 1
    for (int t = 0; t < 16; ++t) {
        if (t < 15) { STAGE_B2(t + 1, (char*)Blds + ((t + 1) & 1) * 16384) }
        const char* Bc = (const char*)Blds + (t & 1) * 16384;
        const int kc = ((t * 4 + quad) ^ hsw) * 16;
        const short8 hv0 = *(const short8*)((const char*)Hbuf + l16 * 1024 + kc);
        const short8 hv1 = *(const short8*)((const char*)Hbuf + (16 + l16) * 1024 + kc);
#pragma unroll
        for (int nf = 0; nf < 4; ++nf) {
            const short8 bv = *(const short8*)(Bc + (size_t)(wave * 64 + nf * 16 + l16) * 64 + swz16);
            a2[0][nf] = MFMA(hv0, bv, a2[0][nf]);
            a2[1][nf] = MFMA(hv1, bv, a2[1][nf]);
        }
        __syncthreads();
    }

    // ---------------- LN epilogue + out ----------------
    f32x4 mu0, rs0, mu1, rs1;
#pragma unroll
    for (int r = 0; r < 4; ++r) {
        const int rl0 = quad * 4 + r, rl1 = 16 + rl0;
        const float s0 = sstat[0][rl0][0] + sstat[1][rl0][0] + sstat[2][rl0][0] + sstat[3][rl0][0];
        const float q0 = sstat[0][rl0][1] + sstat[1][rl0][1] + sstat[2][rl0][1] + sstat[3][rl0][1];
        const float s1 = sstat[0][rl1][0] + sstat[1][rl1][0] + sstat[2][rl1][0] + sstat[3][rl1][0];
        const float q1 = sstat[0][rl1][1] + sstat[1][rl1][1] + sstat[2][rl1][1] + sstat[3][rl1][1];
        mu0[r] = s0 * (1.0f / 512.0f);
        mu1[r] = s1 * (1.0f / 512.0f);
        rs0[r] = rsqrtf(q0 * (1.0f / 512.0f) - mu0[r] * mu0[r] + 1e-5f);
        rs1[r] = rsqrtf(q1 * (1.0f / 512.0f) - mu1[r] * mu1[r] + 1e-5f);
    }
#pragma unroll
    for (int nf = 0; nf < 4; ++nf) {
        const int col = wave * 64 + nf * 16 + l16;
        const float g_ = gw[col], c_ = cvec[col];
#pragma unroll
        for (int r = 0; r < 4; ++r) {
            const int row0 = m0 + quad * 4 + r;
            const int row1 = row0 + 16;
            out[(size_t)row0 * HID + col] = rs0[r] * (a2[0][nf][r] - mu0[r] * g_) + c_;
            out[(size_t)row1 * HID + col] = rs1[r] * (a2[1][nf][r] - mu1[r] * g_) + c_;
        }
    }
}

// ============================================================================
extern "C" void kernel_launch(void* const* d_in, const int* in_sizes, int n_in,
                              void* d_out, int out_size, void* d_ws, size_t ws_size,
                              hipStream_t stream) {
    const float* x   = (const float*)d_in[0];
    const float* w1  = (const float*)d_in[1];
    const float* b1  = (const float*)d_in[2];
    const float* lng = (const float*)d_in[3];
    const float* lnb = (const float*)d_in[4];
    const float* w2  = (const float*)d_in[5];
    const float* b2  = (const float*)d_in[6];
    float* out = (float*)d_out;

    char* ws = (char*)d_ws;
    __hip_bfloat16* feats = (__hip_bfloat16*)(ws);                        // 9437184
    __hip_bfloat16* w1T   = (__hip_bfloat16*)(ws + 9437184);              // 294912 (512x288)
    __hip_bfloat16* w2g   = (__hip_bfloat16*)(ws + 9732096);              // 262144 (256x512)
    float*          gw    = (float*)(ws + 9994240);                       // 1024
    float*          cvec  = (float*)(ws + 9995264);                       // 1024

    prep_kernel<<<dim3(768), dim3(512), 0, stream>>>(w1, w2, lng, lnb, b2,
                                                     w1T, w2g, gw, cvec);
    sig_kernel<<<dim3(8 * SBLK), dim3(192), 0, stream>>>(x, feats);
    mlp_kernel<<<dim3(512), dim3(256), 0, stream>>>(feats, w1T, b1, w2g, gw, cvec, out);
}